// Round 11
// baseline (176.084 us; speedup 1.0000x reference)
//
#include <hip/hip_runtime.h>
#include <hip/hip_bf16.h>
#include <stdint.h>

// Problem constants
#define B_  4096
#define T_  80
#define E_  100
#define U_  64
#define G_  256    // 4*U
#define V_  10000

#define RPB 32     // rows per block: TWO independent 16-row groups (A=rows 0-15,
                   // B=rows 16-31) interleaved in each wave -> 2 dependency
                   // chains of equal length fill each other's latency bubbles.

#define S_H  72    // hbuf row stride (bf16): 144B rows; b128 reads at bank floor
#define AS   136   // embk emb-tile LDS stride (bf16)
#define KS2  132   // embk k1-tile ROW-major LDS stride (bf16)
#define TS   81    // token LDS row stride (ints); odd stride spreads rows across banks
#define XS   260   // xstage row stride (floats); rows n and n+16 have identical bank
                   // phase (16*260 % 32 == 0) -> per-instruction pattern unchanged

typedef __attribute__((ext_vector_type(8))) __bf16 bf16x8;
typedef __attribute__((ext_vector_type(4))) __bf16 bf16x4;
typedef __attribute__((ext_vector_type(4))) float  floatx4;

__device__ __forceinline__ float sigmoidf_(float x) {
    return __builtin_amdgcn_rcpf(1.f + __expf(-x));
}

__device__ __forceinline__ float tanhf_(float x) {
    // 1 - 2/(e^{2x}+1): monotone, saturates correctly, no NaN
    return fmaf(-2.f, __builtin_amdgcn_rcpf(__expf(2.f * x) + 1.f), 1.f);
}

// global -> LDS direct DMA: each lane contributes 16B; LDS dest = wave-uniform
// base + lane*16 (linear). Tracked by vmcnt.
__device__ __forceinline__ void gload16(const float* gsrc, const float* ldst) {
    __builtin_amdgcn_global_load_lds(
        (const __attribute__((address_space(1))) void*)(uintptr_t)gsrc,
        (__attribute__((address_space(3))) void*)(uintptr_t)ldst,
        16, 0, 0);
}

// ---------------------------------------------------------------------------
// Kernel A (MFMA): embk[v][g] = b1[g] + emb[v] . k1[:,g]   (R5/R6, known-good)
// ---------------------------------------------------------------------------
__global__ __launch_bounds__(256) void embk_kernel(const float* __restrict__ emb,
                                                   const float* __restrict__ k1,
                                                   const float* __restrict__ b1,
                                                   float* __restrict__ embk) {
    __shared__ __bf16 aLDS[64 * AS];         // 17.4 KB  (emb tile, row-major)
    __shared__ __bf16 kLDS[128 * KS2];       // 33.8 KB  (k1 tile, ROW-major [k][col])

    const int tid  = threadIdx.x;
    const int lane = tid & 63;
    const int w    = tid >> 6;
    const int n    = lane & 15;
    const int kg   = lane >> 4;
    const int v0   = (blockIdx.x >> 1) * 64;
    const int n0   = (blockIdx.x & 1) * 128;
    const int nrows = min(64, V_ - v0);

    for (int i = tid; i < 64 * AS / 8; i += 256) {
        bf16x8 z;
#pragma unroll
        for (int jj = 0; jj < 8; ++jj) z[jj] = (__bf16)0.f;
        *(bf16x8*)(aLDS + i * 8) = z;
    }
    for (int i = tid; i < 28 * KS2; i += 256)
        kLDS[100 * KS2 + i] = (__bf16)0.f;

    const float bv0 = b1[n0 + w * 32 + n];
    const float bv1 = b1[n0 + w * 32 + 16 + n];

    __syncthreads();

    for (int i = tid; i < nrows * 25; i += 256) {
        int r = i / 25, q = i - r * 25;
        float4 ev = *(const float4*)(emb + (long)(v0 + r) * E_ + q * 4);
        bf16x4 bv; bv[0] = (__bf16)ev.x; bv[1] = (__bf16)ev.y;
                   bv[2] = (__bf16)ev.z; bv[3] = (__bf16)ev.w;
        *(bf16x4*)(aLDS + r * AS + q * 4) = bv;
    }
    for (int i = tid; i < 100 * 32; i += 256) {
        int k = i >> 5, cq = (i & 31) * 4;
        float4 kv = *(const float4*)(k1 + (long)k * G_ + n0 + cq);
        bf16x4 bv; bv[0] = (__bf16)kv.x; bv[1] = (__bf16)kv.y;
                   bv[2] = (__bf16)kv.z; bv[3] = (__bf16)kv.w;
        *(bf16x4*)(kLDS + k * KS2 + cq) = bv;
    }
    __syncthreads();

    bf16x8 bfr[2][4];
#pragma unroll
    for (int ct = 0; ct < 2; ++ct)
#pragma unroll
        for (int kc = 0; kc < 4; ++kc) {
            bf16x8 s;
#pragma unroll
            for (int jj = 0; jj < 8; ++jj)
                s[jj] = kLDS[(kc * 32 + kg * 8 + jj) * KS2 + w * 32 + ct * 16 + n];
            bfr[ct][kc] = s;
        }

#pragma unroll
    for (int mt = 0; mt < 4; ++mt) {
        const __bf16* ab = aLDS + (mt * 16 + n) * AS + kg * 8;
        bf16x8 a0 = *(const bf16x8*)(ab + 0);
        bf16x8 a1 = *(const bf16x8*)(ab + 32);
        bf16x8 a2 = *(const bf16x8*)(ab + 64);
        bf16x8 a3 = *(const bf16x8*)(ab + 96);
#pragma unroll
        for (int ct = 0; ct < 2; ++ct) {
            float bv = ct ? bv1 : bv0;
            floatx4 acc = {bv, bv, bv, bv};
            acc = __builtin_amdgcn_mfma_f32_16x16x32_bf16(a0, bfr[ct][0], acc, 0, 0, 0);
            acc = __builtin_amdgcn_mfma_f32_16x16x32_bf16(a1, bfr[ct][1], acc, 0, 0, 0);
            acc = __builtin_amdgcn_mfma_f32_16x16x32_bf16(a2, bfr[ct][2], acc, 0, 0, 0);
            acc = __builtin_amdgcn_mfma_f32_16x16x32_bf16(a3, bfr[ct][3], acc, 0, 0, 0);
#pragma unroll
            for (int r = 0; r < 4; ++r) {
                int v = v0 + mt * 16 + kg * 4 + r;
                if (v < V_) embk[(long)v * G_ + n0 + w * 32 + ct * 16 + n] = acc[r];
            }
        }
    }
}

// ---------------------------------------------------------------------------
// Kernel B (R11): R6 step schedule, TWO independent 16-row groups per wave.
// Group A = LDS rows 0-15 (c[0..3]), group B = rows 16-31 (c[4..7]); the two
// MFMA/gate/ds chains are data-independent, so each fills the other's
// ds_read (~120cy), MFMA and trans latency bubbles. Total work unchanged
// (grid halves to 128 blocks). One barrier per superstep; counted vmcnt(8)
// (= this superstep's 8 DMAs) guarantees buffers consumed next superstep are
// complete. Same per-row math and order as R6 -> bit-identical output.
// ---------------------------------------------------------------------------
template<int SEL, int RB, int WB>
__device__ __forceinline__ void lstm_step(
        int tt, int n, int kg, int w, int lane,
        const int* __restrict__ tokLDS,
        __bf16 (&hbuf)[2][RPB * S_H],
        float (&xstage)[3][RPB * XS],
        const bf16x8 (&afr)[4][2],
        const float* __restrict__ embk,
        float (&c)[8]) {
    // consumer reads: h^T_{t-1} + xk_t, both groups
    const __bf16* hb = &hbuf[SEL ^ 1][0];
    bf16x8 hA0 = *(const bf16x8*)(hb + n * S_H + kg * 8);
    bf16x8 hA1 = *(const bf16x8*)(hb + n * S_H + 32 + kg * 8);
    bf16x8 hB0 = *(const bf16x8*)(hb + (16 + n) * S_H + kg * 8);
    bf16x8 hB1 = *(const bf16x8*)(hb + (16 + n) * S_H + 32 + kg * 8);
    const float* xrA = &xstage[RB][0] + n * XS + w * 16 + kg * 4;
    const float* xrB = xrA + 16 * XS;                 // compile-time offset
    floatx4 a0 = *(const floatx4*)(xrA + 0);
    floatx4 a1 = *(const floatx4*)(xrA + 64);
    floatx4 a2 = *(const floatx4*)(xrA + 128);
    floatx4 a3 = *(const floatx4*)(xrA + 192);
    floatx4 b0 = *(const floatx4*)(xrB + 0);
    floatx4 b1 = *(const floatx4*)(xrB + 64);
    floatx4 b2 = *(const floatx4*)(xrB + 128);
    floatx4 b3 = *(const floatx4*)(xrB + 192);

    // producer: DMA xk(t+2), 4 rows per group (fire-and-forget)
#pragma unroll
    for (int j = 0; j < 4; ++j) {
        int tokA = tokLDS[(w * 4 + j) * TS + tt];
        gload16(embk + (long)tokA * G_ + (lane << 2),
                &xstage[WB][0] + (w * 4 + j) * XS);
        int tokB = tokLDS[(16 + w * 4 + j) * TS + tt];
        gload16(embk + (long)tokB * G_ + (lane << 2),
                &xstage[WB][0] + (16 + w * 4 + j) * XS);
    }

    // z^T tiles, both groups (independent MFMA chains)
    a0 = __builtin_amdgcn_mfma_f32_16x16x32_bf16(afr[0][0], hA0, a0, 0, 0, 0);
    b0 = __builtin_amdgcn_mfma_f32_16x16x32_bf16(afr[0][0], hB0, b0, 0, 0, 0);
    a0 = __builtin_amdgcn_mfma_f32_16x16x32_bf16(afr[0][1], hA1, a0, 0, 0, 0);
    b0 = __builtin_amdgcn_mfma_f32_16x16x32_bf16(afr[0][1], hB1, b0, 0, 0, 0);
    a1 = __builtin_amdgcn_mfma_f32_16x16x32_bf16(afr[1][0], hA0, a1, 0, 0, 0);
    b1 = __builtin_amdgcn_mfma_f32_16x16x32_bf16(afr[1][0], hB0, b1, 0, 0, 0);
    a1 = __builtin_amdgcn_mfma_f32_16x16x32_bf16(afr[1][1], hA1, a1, 0, 0, 0);
    b1 = __builtin_amdgcn_mfma_f32_16x16x32_bf16(afr[1][1], hB1, b1, 0, 0, 0);
    a2 = __builtin_amdgcn_mfma_f32_16x16x32_bf16(afr[2][0], hA0, a2, 0, 0, 0);
    b2 = __builtin_amdgcn_mfma_f32_16x16x32_bf16(afr[2][0], hB0, b2, 0, 0, 0);
    a2 = __builtin_amdgcn_mfma_f32_16x16x32_bf16(afr[2][1], hA1, a2, 0, 0, 0);
    b2 = __builtin_amdgcn_mfma_f32_16x16x32_bf16(afr[2][1], hB1, b2, 0, 0, 0);
    a3 = __builtin_amdgcn_mfma_f32_16x16x32_bf16(afr[3][0], hA0, a3, 0, 0, 0);
    b3 = __builtin_amdgcn_mfma_f32_16x16x32_bf16(afr[3][0], hB0, b3, 0, 0, 0);
    a3 = __builtin_amdgcn_mfma_f32_16x16x32_bf16(afr[3][1], hA1, a3, 0, 0, 0);
    b3 = __builtin_amdgcn_mfma_f32_16x16x32_bf16(afr[3][1], hB1, b3, 0, 0, 0);

    // gates, both groups (independent trans chains interleave on the pipe)
    bf16x4 hvA, hvB;
#pragma unroll
    for (int r = 0; r < 4; ++r) {
        float zi = a0[r], zf = a1[r], zg = a2[r], zo = a3[r];
        float cn = fmaf(sigmoidf_(zf), c[r], sigmoidf_(zi) * tanhf_(zg));
        float hn = sigmoidf_(zo) * tanhf_(cn);
        c[r] = cn;
        hvA[r] = (__bf16)hn;
    }
#pragma unroll
    for (int r = 0; r < 4; ++r) {
        float zi = b0[r], zf = b1[r], zg = b2[r], zo = b3[r];
        float cn = fmaf(sigmoidf_(zf), c[4 + r], sigmoidf_(zi) * tanhf_(zg));
        float hn = sigmoidf_(zo) * tanhf_(cn);
        c[4 + r] = cn;
        hvB[r] = (__bf16)hn;
    }
    *(bf16x4*)(&hbuf[SEL][0] + n * S_H + w * 16 + kg * 4) = hvA;
    *(bf16x4*)(&hbuf[SEL][0] + (16 + n) * S_H + w * 16 + kg * 4) = hvB;

    // LDS drained; only this superstep's 8 DMA loads may remain in flight.
    asm volatile("s_waitcnt lgkmcnt(0) vmcnt(8)\n\ts_barrier" ::: "memory");
}

__global__ __launch_bounds__(256) void lstm_kernel(const int*   __restrict__ tokens,
                                                   const float* __restrict__ embk,
                                                   const float* __restrict__ r1,
                                                   const float* __restrict__ Wd,
                                                   const float* __restrict__ bd,
                                                   float* __restrict__ out) {
    __shared__ int    tokLDS[RPB * TS];      // 10.4 KB
    __shared__ __bf16 hbuf[2][RPB * S_H];    // 9.2 KB
    __shared__ float  xstage[3][RPB * XS];   // 99.8 KB (3-phase rotation, 2 groups)

    const int tid  = threadIdx.x;
    const int lane = tid & 63;
    const int w    = tid >> 6;               // unit block [w*16, w*16+16), both groups
    const int n    = lane & 15;              // batch row within group
    const int kg   = lane >> 4;              // 0..3
    const int bb   = blockIdx.x * RPB;

    for (int i = tid; i < RPB * T_; i += 256)
        tokLDS[(i / T_) * TS + (i % T_)] = tokens[bb * T_ + i];
    for (int i = tid; i < 2 * RPB * S_H; i += 256) (&hbuf[0][0])[i] = (__bf16)0.f;

    // A-fragments = r1^T (static, SHARED by both groups)
    bf16x8 afr[4][2];
#pragma unroll
    for (int ct = 0; ct < 4; ++ct)
#pragma unroll
        for (int kc = 0; kc < 2; ++kc) {
            bf16x8 s;
#pragma unroll
            for (int jj = 0; jj < 8; ++jj)
                s[jj] = (__bf16)r1[(kc * 32 + kg * 8 + jj) * G_ + ct * 64 + w * 16 + n];
            afr[ct][kc] = s;
        }

    float c[8] = {0.f, 0.f, 0.f, 0.f, 0.f, 0.f, 0.f, 0.f};

    __syncthreads();      // tokens/hbuf visible; clean vmcnt base

    // prologue: DMA slots 0 (t=0) and 1 (t=1) for both groups; vmcnt(8) ->
    // slot 0 (issued first, 8 loads) complete.
#pragma unroll
    for (int s = 0; s < 2; ++s)
#pragma unroll
        for (int j = 0; j < 4; ++j) {
            int tokA = tokLDS[(w * 4 + j) * TS + s];
            gload16(embk + (long)tokA * G_ + (lane << 2),
                    &xstage[s][0] + (w * 4 + j) * XS);
            int tokB = tokLDS[(16 + w * 4 + j) * TS + s];
            gload16(embk + (long)tokB * G_ + (lane << 2),
                    &xstage[s][0] + (16 + w * 4 + j) * XS);
        }
    asm volatile("s_waitcnt lgkmcnt(0) vmcnt(8)\n\ts_barrier" ::: "memory");

    // 78 = 13*6 supersteps (lcm of buffer period 3, parity 2), then 2 tail.
    for (int t = 0; t < 78; t += 6) {
        lstm_step<0, 0, 2>(t + 2, n, kg, w, lane, tokLDS, hbuf, xstage, afr, embk, c);
        lstm_step<1, 1, 0>(t + 3, n, kg, w, lane, tokLDS, hbuf, xstage, afr, embk, c);
        lstm_step<0, 2, 1>(t + 4, n, kg, w, lane, tokLDS, hbuf, xstage, afr, embk, c);
        lstm_step<1, 0, 2>(t + 5, n, kg, w, lane, tokLDS, hbuf, xstage, afr, embk, c);
        lstm_step<0, 1, 0>(t + 6, n, kg, w, lane, tokLDS, hbuf, xstage, afr, embk, c);
        lstm_step<1, 2, 1>(t + 7, n, kg, w, lane, tokLDS, hbuf, xstage, afr, embk, c);
    }
    lstm_step<0, 0, 2>(79, n, kg, w, lane, tokLDS, hbuf, xstage, afr, embk, c); // t=78
    lstm_step<1, 1, 0>(79, n, kg, w, lane, tokLDS, hbuf, xstage, afr, embk, c); // t=79

    // drain remaining DMA before the epilogue reads LDS
    asm volatile("s_waitcnt vmcnt(0)" ::: "memory");

    // out[b] = sigmoid(h_final[b] . Wd + bd); h_79 in hbuf[1], rows 0..31
    if (tid < RPB) {
        const __bf16* hb = hbuf[1] + tid * S_H;
        float s = bd[0];
#pragma unroll
        for (int u = 0; u < U_; ++u) s = fmaf((float)hb[u], Wd[u], s);
        out[bb + tid] = sigmoidf_(s);
    }
}

// ---------------------------------------------------------------------------
extern "C" void kernel_launch(void* const* d_in, const int* in_sizes, int n_in,
                              void* d_out, int out_size, void* d_ws, size_t ws_size,
                              hipStream_t stream) {
    const int*   tokens = (const int*)  d_in[0];
    const float* emb    = (const float*)d_in[1];
    // d_in[2..4] = k0, r0, b0 : dead in the reference (cell0 state unused)
    const float* k1     = (const float*)d_in[5];
    const float* r1     = (const float*)d_in[6];
    const float* b1     = (const float*)d_in[7];
    const float* Wd     = (const float*)d_in[8];
    const float* bd     = (const float*)d_in[9];
    float*       out    = (float*)d_out;

    float* embk = (float*)d_ws;              // V_*G_ floats = 10.24 MB

    embk_kernel<<<((V_ + 63) / 64) * 2, 256, 0, stream>>>(emb, k1, b1, embk);
    lstm_kernel<<<B_ / RPB, 256, 0, stream>>>(tokens, embk, r1, Wd, bd, out);
}

// Round 12
// 129.581 us; speedup vs baseline: 1.3589x; 1.3589x over previous
//
#include <hip/hip_runtime.h>
#include <hip/hip_bf16.h>
#include <stdint.h>

// Problem constants
#define B_  4096
#define T_  80
#define E_  100
#define U_  64
#define G_  256    // 4*U
#define V_  10000

#define RPB 8      // REAL rows per block. 512 blocks -> 2 blocks/CU (R7's proven
                   // desync-fill mechanism) but with NO mirror waste: gate work
                   // is split r-wise across the lane pairs (n, n+8) whose MFMA
                   // accumulators are bit-identical (mirrored B columns), so
                   // each wave issues HALF the R6 gate work (2 cells/lane).

#define S_H  72    // hbuf row stride (bf16): 144B rows
#define AS   136   // embk emb-tile LDS stride (bf16)
#define KS2  132   // embk k1-tile ROW-major LDS stride (bf16)
#define TS   81    // token LDS row stride (ints)
#define XS   260   // xstage row stride (floats)

typedef __attribute__((ext_vector_type(8))) __bf16 bf16x8;
typedef __attribute__((ext_vector_type(4))) __bf16 bf16x4;
typedef __attribute__((ext_vector_type(2))) __bf16 bf16x2;
typedef __attribute__((ext_vector_type(4))) float  floatx4;

__device__ __forceinline__ float sigmoidf_(float x) {
    return __builtin_amdgcn_rcpf(1.f + __expf(-x));
}

__device__ __forceinline__ float tanhf_(float x) {
    // 1 - 2/(e^{2x}+1): monotone, saturates correctly, no NaN
    return fmaf(-2.f, __builtin_amdgcn_rcpf(__expf(2.f * x) + 1.f), 1.f);
}

// global -> LDS direct DMA: each lane contributes 16B; LDS dest = wave-uniform
// base + lane*16 (linear). Tracked by vmcnt.
__device__ __forceinline__ void gload16(const float* gsrc, const float* ldst) {
    __builtin_amdgcn_global_load_lds(
        (const __attribute__((address_space(1))) void*)(uintptr_t)gsrc,
        (__attribute__((address_space(3))) void*)(uintptr_t)ldst,
        16, 0, 0);
}

// ---------------------------------------------------------------------------
// Kernel A (MFMA): embk[v][g] = b1[g] + emb[v] . k1[:,g]   (R5/R6, known-good)
// ---------------------------------------------------------------------------
__global__ __launch_bounds__(256) void embk_kernel(const float* __restrict__ emb,
                                                   const float* __restrict__ k1,
                                                   const float* __restrict__ b1,
                                                   float* __restrict__ embk) {
    __shared__ __bf16 aLDS[64 * AS];         // 17.4 KB  (emb tile, row-major)
    __shared__ __bf16 kLDS[128 * KS2];       // 33.8 KB  (k1 tile, ROW-major [k][col])

    const int tid  = threadIdx.x;
    const int lane = tid & 63;
    const int w    = tid >> 6;
    const int n    = lane & 15;
    const int kg   = lane >> 4;
    const int v0   = (blockIdx.x >> 1) * 64;
    const int n0   = (blockIdx.x & 1) * 128;
    const int nrows = min(64, V_ - v0);

    for (int i = tid; i < 64 * AS / 8; i += 256) {
        bf16x8 z;
#pragma unroll
        for (int jj = 0; jj < 8; ++jj) z[jj] = (__bf16)0.f;
        *(bf16x8*)(aLDS + i * 8) = z;
    }
    for (int i = tid; i < 28 * KS2; i += 256)
        kLDS[100 * KS2 + i] = (__bf16)0.f;

    const float bv0 = b1[n0 + w * 32 + n];
    const float bv1 = b1[n0 + w * 32 + 16 + n];

    __syncthreads();

    for (int i = tid; i < nrows * 25; i += 256) {
        int r = i / 25, q = i - r * 25;
        float4 ev = *(const float4*)(emb + (long)(v0 + r) * E_ + q * 4);
        bf16x4 bv; bv[0] = (__bf16)ev.x; bv[1] = (__bf16)ev.y;
                   bv[2] = (__bf16)ev.z; bv[3] = (__bf16)ev.w;
        *(bf16x4*)(aLDS + r * AS + q * 4) = bv;
    }
    for (int i = tid; i < 100 * 32; i += 256) {
        int k = i >> 5, cq = (i & 31) * 4;
        float4 kv = *(const float4*)(k1 + (long)k * G_ + n0 + cq);
        bf16x4 bv; bv[0] = (__bf16)kv.x; bv[1] = (__bf16)kv.y;
                   bv[2] = (__bf16)kv.z; bv[3] = (__bf16)kv.w;
        *(bf16x4*)(kLDS + k * KS2 + cq) = bv;
    }
    __syncthreads();

    bf16x8 bfr[2][4];
#pragma unroll
    for (int ct = 0; ct < 2; ++ct)
#pragma unroll
        for (int kc = 0; kc < 4; ++kc) {
            bf16x8 s;
#pragma unroll
            for (int jj = 0; jj < 8; ++jj)
                s[jj] = kLDS[(kc * 32 + kg * 8 + jj) * KS2 + w * 32 + ct * 16 + n];
            bfr[ct][kc] = s;
        }

#pragma unroll
    for (int mt = 0; mt < 4; ++mt) {
        const __bf16* ab = aLDS + (mt * 16 + n) * AS + kg * 8;
        bf16x8 a0 = *(const bf16x8*)(ab + 0);
        bf16x8 a1 = *(const bf16x8*)(ab + 32);
        bf16x8 a2 = *(const bf16x8*)(ab + 64);
        bf16x8 a3 = *(const bf16x8*)(ab + 96);
#pragma unroll
        for (int ct = 0; ct < 2; ++ct) {
            float bv = ct ? bv1 : bv0;
            floatx4 acc = {bv, bv, bv, bv};
            acc = __builtin_amdgcn_mfma_f32_16x16x32_bf16(a0, bfr[ct][0], acc, 0, 0, 0);
            acc = __builtin_amdgcn_mfma_f32_16x16x32_bf16(a1, bfr[ct][1], acc, 0, 0, 0);
            acc = __builtin_amdgcn_mfma_f32_16x16x32_bf16(a2, bfr[ct][2], acc, 0, 0, 0);
            acc = __builtin_amdgcn_mfma_f32_16x16x32_bf16(a3, bfr[ct][3], acc, 0, 0, 0);
#pragma unroll
            for (int r = 0; r < 4; ++r) {
                int v = v0 + mt * 16 + kg * 4 + r;
                if (v < V_) embk[(long)v * G_ + n0 + w * 32 + ct * 16 + n] = acc[r];
            }
        }
    }
}

// ---------------------------------------------------------------------------
// Kernel B (R12): R6 step schedule at 8 REAL rows/block, 512 blocks, 2/CU.
// MFMA keeps N=16 by mirroring batch rows 8-15 onto 0-7 (B-fragment and xk
// C-init read row n&7: same-address 2-way broadcast = free). Because the
// mirrored B columns make lane (n+8,kg)'s accumulator BIT-IDENTICAL to lane
// (n,kg)'s, the gate work is split r-wise with zero communication:
//   lane n<8  gates acc[.][0..1] -> cells (row n,   units kg*4+{0,1})
//   lane n>=8 gates acc[.][2..3] -> cells (row n-8, units kg*4+{2,3})
// -> 2 cells/lane (half of R6's 4): 20 trans + ~60 VALU per wave-step.
// Two desynchronized blocks per CU (R7's verified fill mechanism) absorb the
// chain/barrier stall with REAL work this time. Per-cell math is
// operation-identical to R6 -> bit-identical output.
// ---------------------------------------------------------------------------
template<int SEL, int RB, int WB>
__device__ __forceinline__ void lstm_step(
        int tt, int n7, int hi, int kg, int w, int lane,
        const int* __restrict__ tokLDS,
        __bf16 (&hbuf)[2][RPB * S_H],
        float (&xstage)[3][RPB * XS],
        const bf16x8 (&afr)[4][2],
        const float* __restrict__ embk,
        float (&c)[2]) {
    // consumer reads: h^T_{t-1} + xk_t (row n&7; lanes n and n+8 broadcast)
    const __bf16* hb = &hbuf[SEL ^ 1][0];
    bf16x8 hb0 = *(const bf16x8*)(hb + n7 * S_H + kg * 8);
    bf16x8 hb1 = *(const bf16x8*)(hb + n7 * S_H + 32 + kg * 8);
    const float* xrow = &xstage[RB][0] + n7 * XS + w * 16 + kg * 4;
    floatx4 a0 = *(const floatx4*)(xrow + 0);
    floatx4 a1 = *(const floatx4*)(xrow + 64);
    floatx4 a2 = *(const floatx4*)(xrow + 128);
    floatx4 a3 = *(const floatx4*)(xrow + 192);

    // producer: DMA xk(t+2) rows w*2, w*2+1 into xstage[WB] (fire-and-forget)
#pragma unroll
    for (int j = 0; j < 2; ++j) {
        int tok = tokLDS[(w * 2 + j) * TS + tt];
        gload16(embk + (long)tok * G_ + (lane << 2),
                &xstage[WB][0] + (w * 2 + j) * XS);
    }

    // z^T tiles: acc[ct] = r1^T @ h^T + xk   (cols 8-15 = exact mirrors)
    a0 = __builtin_amdgcn_mfma_f32_16x16x32_bf16(afr[0][0], hb0, a0, 0, 0, 0);
    a0 = __builtin_amdgcn_mfma_f32_16x16x32_bf16(afr[0][1], hb1, a0, 0, 0, 0);
    a1 = __builtin_amdgcn_mfma_f32_16x16x32_bf16(afr[1][0], hb0, a1, 0, 0, 0);
    a1 = __builtin_amdgcn_mfma_f32_16x16x32_bf16(afr[1][1], hb1, a1, 0, 0, 0);
    a2 = __builtin_amdgcn_mfma_f32_16x16x32_bf16(afr[2][0], hb0, a2, 0, 0, 0);
    a2 = __builtin_amdgcn_mfma_f32_16x16x32_bf16(afr[2][1], hb1, a2, 0, 0, 0);
    a3 = __builtin_amdgcn_mfma_f32_16x16x32_bf16(afr[3][0], hb0, a3, 0, 0, 0);
    a3 = __builtin_amdgcn_mfma_f32_16x16x32_bf16(afr[3][1], hb1, a3, 0, 0, 0);

    // gates: 2 cells/lane. hi-lanes use their own acc[.][2..3] (== lo-lane's
    // values, mirror-identical). a0=i, a1=f, a2=g, a3=o. Static indices only.
    float zi0 = hi ? a0[2] : a0[0], zi1 = hi ? a0[3] : a0[1];
    float zf0 = hi ? a1[2] : a1[0], zf1 = hi ? a1[3] : a1[1];
    float zg0 = hi ? a2[2] : a2[0], zg1 = hi ? a2[3] : a2[1];
    float zo0 = hi ? a3[2] : a3[0], zo1 = hi ? a3[3] : a3[1];

    bf16x2 hv;
    {
        float cn = fmaf(sigmoidf_(zf0), c[0], sigmoidf_(zi0) * tanhf_(zg0));
        float hn = sigmoidf_(zo0) * tanhf_(cn);
        c[0] = cn; hv[0] = (__bf16)hn;
    }
    {
        float cn = fmaf(sigmoidf_(zf1), c[1], sigmoidf_(zi1) * tanhf_(zg1));
        float hn = sigmoidf_(zo1) * tanhf_(cn);
        c[1] = cn; hv[1] = (__bf16)hn;
    }
    // h_new: lane n<8 writes units kg*4+{0,1}, lane n+8 writes kg*4+{2,3}
    *(bf16x2*)(&hbuf[SEL][0] + n7 * S_H + w * 16 + kg * 4 + hi * 2) = hv;

    // LDS drained; only this step's 2 DMA loads may remain in flight.
    asm volatile("s_waitcnt lgkmcnt(0) vmcnt(2)\n\ts_barrier" ::: "memory");
}

__global__ __launch_bounds__(256, 2) void lstm_kernel(const int*   __restrict__ tokens,
                                                      const float* __restrict__ embk,
                                                      const float* __restrict__ r1,
                                                      const float* __restrict__ Wd,
                                                      const float* __restrict__ bd,
                                                      float* __restrict__ out) {
    __shared__ int    tokLDS[RPB * TS];      // 2.6 KB
    __shared__ __bf16 hbuf[2][RPB * S_H];    // 2.3 KB
    __shared__ float  xstage[3][RPB * XS];   // 25.0 KB  (total ~30 KB -> 2 blocks/CU)

    const int tid  = threadIdx.x;
    const int lane = tid & 63;
    const int w    = tid >> 6;               // unit block [w*16, w*16+16)
    const int n    = lane & 15;              // MFMA N index (batch row, mirrored >=8)
    const int n7   = n & 7;                  // real batch row
    const int hi   = (n >> 3) & 1;           // r-half this lane gates
    const int kg   = lane >> 4;              // 0..3
    const int bb   = blockIdx.x * RPB;

    for (int i = tid; i < RPB * T_; i += 256)
        tokLDS[(i / T_) * TS + (i % T_)] = tokens[bb * T_ + i];
    for (int i = tid; i < 2 * RPB * S_H; i += 256) (&hbuf[0][0])[i] = (__bf16)0.f;

    // A-fragments = r1^T (static): tile ct covers gate-cols ct*64 + w*16 + m
    bf16x8 afr[4][2];
#pragma unroll
    for (int ct = 0; ct < 4; ++ct)
#pragma unroll
        for (int kc = 0; kc < 2; ++kc) {
            bf16x8 s;
#pragma unroll
            for (int jj = 0; jj < 8; ++jj)
                s[jj] = (__bf16)r1[(kc * 32 + kg * 8 + jj) * G_ + ct * 64 + w * 16 + n];
            afr[ct][kc] = s;
        }

    float c[2] = {0.f, 0.f};

    __syncthreads();      // tokens/hbuf visible; clean vmcnt base

    // prologue: DMA xstage[0] (t=0) then xstage[1] (t=1); wait oldest 2 done.
#pragma unroll
    for (int s = 0; s < 2; ++s)
#pragma unroll
        for (int j = 0; j < 2; ++j) {
            int tok = tokLDS[(w * 2 + j) * TS + s];
            gload16(embk + (long)tok * G_ + (lane << 2),
                    &xstage[s][0] + (w * 2 + j) * XS);
        }
    asm volatile("s_waitcnt lgkmcnt(0) vmcnt(2)\n\ts_barrier" ::: "memory");

    // 78 = 13*6 steps (lcm of buffer period 3, parity 2), then 2 tail steps.
    for (int t = 0; t < 78; t += 6) {
        lstm_step<0, 0, 2>(t + 2, n7, hi, kg, w, lane, tokLDS, hbuf, xstage, afr, embk, c);
        lstm_step<1, 1, 0>(t + 3, n7, hi, kg, w, lane, tokLDS, hbuf, xstage, afr, embk, c);
        lstm_step<0, 2, 1>(t + 4, n7, hi, kg, w, lane, tokLDS, hbuf, xstage, afr, embk, c);
        lstm_step<1, 0, 2>(t + 5, n7, hi, kg, w, lane, tokLDS, hbuf, xstage, afr, embk, c);
        lstm_step<0, 1, 0>(t + 6, n7, hi, kg, w, lane, tokLDS, hbuf, xstage, afr, embk, c);
        lstm_step<1, 2, 1>(t + 7, n7, hi, kg, w, lane, tokLDS, hbuf, xstage, afr, embk, c);
    }
    lstm_step<0, 0, 2>(79, n7, hi, kg, w, lane, tokLDS, hbuf, xstage, afr, embk, c); // t=78
    lstm_step<1, 1, 0>(79, n7, hi, kg, w, lane, tokLDS, hbuf, xstage, afr, embk, c); // t=79

    // drain remaining DMA before the epilogue reads LDS
    asm volatile("s_waitcnt vmcnt(0)" ::: "memory");

    // out[b] = sigmoid(h_final[b] . Wd + bd); h_79 in hbuf[1], rows 0..7
    if (tid < RPB) {
        const __bf16* hb = hbuf[1] + tid * S_H;
        float s = bd[0];
#pragma unroll
        for (int u = 0; u < U_; ++u) s = fmaf((float)hb[u], Wd[u], s);
        out[bb + tid] = sigmoidf_(s);
    }
}

// ---------------------------------------------------------------------------
extern "C" void kernel_launch(void* const* d_in, const int* in_sizes, int n_in,
                              void* d_out, int out_size, void* d_ws, size_t ws_size,
                              hipStream_t stream) {
    const int*   tokens = (const int*)  d_in[0];
    const float* emb    = (const float*)d_in[1];
    // d_in[2..4] = k0, r0, b0 : dead in the reference (cell0 state unused)
    const float* k1     = (const float*)d_in[5];
    const float* r1     = (const float*)d_in[6];
    const float* b1     = (const float*)d_in[7];
    const float* Wd     = (const float*)d_in[8];
    const float* bd     = (const float*)d_in[9];
    float*       out    = (float*)d_out;

    float* embk = (float*)d_ws;              // V_*G_ floats = 10.24 MB

    embk_kernel<<<((V_ + 63) / 64) * 2, 256, 0, stream>>>(emb, k1, b1, embk);
    lstm_kernel<<<B_ / RPB, 256, 0, stream>>>(tokens, embk, r1, Wd, bd, out);
}